// Round 1
// baseline (1069.726 us; speedup 1.0000x reference)
//
#include <hip/hip_runtime.h>

// FourierBlock: per (b, c): rfft(4096) -> keep top-16 |X| bins -> irfft.
// One 512-thread block = one batch b x one float4 channel column (4 channels).
// Two 256-thread halves each run a packed-pair complex FFT in a 32 KiB LDS
// buffer (radix-16 DIF, 3 passes, XOR-swizzled banks). Wave-local top-16
// selection, sparse Hermitian rebuild, inverse via conj->fwd->conj.

#define SWZ(i) ((i) ^ (((i) >> 4) & 15))

__device__ __forceinline__ int drev16(int x) {
  // reverse the three base-16 digits of a 12-bit index
  return ((x & 15) << 8) | (x & 0xF0) | ((x >> 8) & 15);
}

__device__ __forceinline__ float2 cmulf(float2 a, float c, float s) {
  return make_float2(a.x * c - a.y * s, a.x * s + a.y * c);
}

__device__ __forceinline__ void bfly4(float2& a0, float2& a1, float2& a2, float2& a3) {
  float ar = a0.x + a2.x, ai = a0.y + a2.y;
  float br = a0.x - a2.x, bi = a0.y - a2.y;
  float cr = a1.x + a3.x, ci = a1.y + a3.y;
  float dr = a1.x - a3.x, di = a1.y - a3.y;
  a0 = make_float2(ar + cr, ai + ci);
  a1 = make_float2(br + di, bi - dr);   // b - i*d
  a2 = make_float2(ar - cr, ai - ci);
  a3 = make_float2(br - di, bi + dr);   // b + i*d
}

// 16-point DIF DFT in registers; output slot s holds bin rev4(s).
__device__ __forceinline__ void dft16(float2* v) {
  const float C16[10] = {1.f, 0.9238795325112867f, 0.7071067811865476f, 0.3826834323650898f, 0.f,
                         -0.3826834323650898f, -0.7071067811865476f, -0.9238795325112867f, -1.f,
                         -0.9238795325112867f};
  const float S16[10] = {0.f, -0.3826834323650898f, -0.7071067811865476f, -0.9238795325112867f, -1.f,
                         -0.9238795325112867f, -0.7071067811865476f, -0.3826834323650898f, 0.f,
                         0.3826834323650898f};
  #pragma unroll
  for (int j2 = 0; j2 < 4; j2++) {
    bfly4(v[j2], v[j2 + 4], v[j2 + 8], v[j2 + 12]);
    if (j2 > 0) {
      v[j2 + 4]  = cmulf(v[j2 + 4],  C16[j2],     S16[j2]);
      v[j2 + 8]  = cmulf(v[j2 + 8],  C16[2 * j2], S16[2 * j2]);
      v[j2 + 12] = cmulf(v[j2 + 12], C16[3 * j2], S16[3 * j2]);
    }
  }
  #pragma unroll
  for (int r2 = 0; r2 < 4; r2++) bfly4(v[4 * r2], v[4 * r2 + 1], v[4 * r2 + 2], v[4 * r2 + 3]);
}

// One radix-16 DIF pass over a span; M = twiddle span (0 = last pass, none).
template <int STRIDE, int M>
__device__ __forceinline__ void fft_pass(float2* Zl, int base, int j) {
  const int kRev4[16] = {0, 4, 8, 12, 1, 5, 9, 13, 2, 6, 10, 14, 3, 7, 11, 15};
  float2 v[16];
  #pragma unroll
  for (int p = 0; p < 16; p++) v[p] = Zl[SWZ(base + j + STRIDE * p)];
  dft16(v);
  #pragma unroll
  for (int r = 0; r < 16; r++) {
    float2 u = v[kRev4[r]];
    if (M > 0 && r > 0) {
      int a = (j * r) & (M - 1);
      if (a > M / 2) a -= M;
      float ang = (float)a * (-6.2831853071795864769f / (float)M);
      float s, c;
      __sincosf(ang, &s, &c);
      u = cmulf(u, c, s);
    }
    Zl[SWZ(base + j + STRIDE * r)] = u;
  }
}

__global__ __launch_bounds__(512, 4) void fourier_topk_kernel(
    const float4* __restrict__ X4, float4* __restrict__ O4) {
  __shared__ float2 Za[4096];
  __shared__ float2 Zb[4096];

  const int tid = threadIdx.x;
  const int idx = blockIdx.x;
  // Swizzle so the 4 blocks sharing a 64B input/output sector land on one XCD
  // (same blockIdx % 8) and are dispatched close in time.
  const int G = idx & 511;     // (b, 16-channel group)
  const int sub = idx >> 9;    // 0..3
  const int b = G >> 3;
  const int q = ((G & 7) << 2) | sub;  // float4 column, 0..31

  const float4* xg = X4 + (size_t)b * 4096 * 32 + q;

  // ---- load: channels 4q..4q+3; pair (x,y) -> Za, (z,w) -> Zb ----
  #pragma unroll
  for (int k = 0; k < 8; k++) {
    int n = tid + 512 * k;
    float4 vv = xg[(size_t)n * 32];
    Za[SWZ(n)] = make_float2(vv.x, vv.y);
    Zb[SWZ(n)] = make_float2(vv.z, vv.w);
  }
  __syncthreads();

  const int h = tid >> 8;      // half: 0 -> Za, 1 -> Zb
  const int lt = tid & 255;    // thread id within half
  float2* Zl = h ? Zb : Za;

  // ---- forward FFT (3 radix-16 passes), output hex-digit-reversed ----
  fft_pass<256, 4096>(Zl, 0, lt);
  __syncthreads();
  fft_pass<16, 256>(Zl, (lt >> 4) << 8, lt & 15);
  __syncthreads();
  fft_pass<1, 0>(Zl, lt << 4, 0);
  __syncthreads();

  // ---- top-16 selection: wave 0 of half = channel 0, wave 1 = channel 1 ----
  const int wv = lt >> 6;      // wave within half
  const int lane = lt & 63;
  int rF = 0; float rA = 0.f, rB = 0.f;   // captured winner (lanes 0..15)

  if (wv < 2) {
    const int ch = wv;
    float m2[32];
    #pragma unroll
    for (int k = 0; k < 32; k++) {
      int f = lane + (k << 6);
      float2 P = Zl[SWZ(drev16(f))];
      float2 Q = Zl[SWZ(drev16((4096 - f) & 4095))];
      float xr = ch ? (P.y + Q.y) : (P.x + Q.x);
      float xi = ch ? (Q.x - P.x) : (P.y - Q.y);
      m2[k] = xr * xr + xi * xi;   // 4*|X|^2 (uniform scale, ordering only)
    }
    float m2x = -1.f;              // bin f=2048 (Nyquist), lane 0 only
    if (lane == 0) {
      float2 P = Zl[SWZ(8)];       // drev16(2048) == 8
      float t = ch ? P.y : P.x;
      m2x = 4.f * t * t;
    }
    for (int r = 0; r < 16; r++) {
      float bv = -1e30f; int bf = 0;
      #pragma unroll
      for (int k = 0; k < 32; k++) {
        int f = lane + (k << 6);
        if (m2[k] > bv) { bv = m2[k]; bf = f; }   // ascending k: ties -> lower f
      }
      if (m2x > bv) { bv = m2x; bf = 2048; }
      #pragma unroll
      for (int off = 32; off; off >>= 1) {
        float ov = __shfl_down(bv, off);
        int   of = __shfl_down(bf, off);
        if (ov > bv || (ov == bv && of < bf)) { bv = ov; bf = of; }
      }
      bf = __shfl(bf, 0);          // broadcast winner bin
      if (lane == r) {             // capture X[bf] in lane r's registers
        rF = bf;
        float2 P = Zl[SWZ(drev16(bf))];
        float2 Q = Zl[SWZ(drev16((4096 - bf) & 4095))];
        rA = ch ? 0.5f * (P.y + Q.y) : 0.5f * (P.x + Q.x);
        rB = ch ? 0.5f * (Q.x - P.x) : 0.5f * (P.y - Q.y);
      }
      if (bf == 2048) {
        if (lane == 0) m2x = -2.f;
      } else if ((bf & 63) == lane) {
        int kk = bf >> 6;
        #pragma unroll
        for (int k = 0; k < 32; k++) if (k == kk) m2[k] = -2.f;
      }
    }
  }
  __syncthreads();   // all spectrum reads done

  // ---- build C = conj(masked Hermitian spectrum), natural order ----
  #pragma unroll
  for (int k = 0; k < 8; k++) {
    int n = tid + 512 * k;
    Za[n] = make_float2(0.f, 0.f);
    Zb[n] = make_float2(0.f, 0.f);
  }
  __syncthreads();
  if (wv == 0 && lane < 16) {      // channel 0: C[f] = conj(X0); C[M] = X0
    int f = rF;
    Zl[SWZ(f)] = make_float2(rA, -rB);
    if (f != 0 && f != 2048) Zl[SWZ(4096 - f)] = make_float2(rA, rB);
  }
  __syncthreads();
  if (wv == 1 && lane < 16) {      // channel 1: C[f] += conj(i*X1); C[M] += conj(i*conj(X1))
    int f = rF;
    float2 u = Zl[SWZ(f)];
    u.x -= rB; u.y -= rA;
    Zl[SWZ(f)] = u;
    if (f != 0 && f != 2048) {
      float2 u2 = Zl[SWZ(4096 - f)];
      u2.x += rB; u2.y -= rA;
      Zl[SWZ(4096 - f)] = u2;
    }
  }
  __syncthreads();

  // ---- inverse: ifft(Z') = conj(fft(conj(Z')))/N ----
  fft_pass<256, 4096>(Zl, 0, lt);
  __syncthreads();
  fft_pass<16, 256>(Zl, (lt >> 4) << 8, lt & 15);
  __syncthreads();
  fft_pass<1, 0>(Zl, lt << 4, 0);
  __syncthreads();

  // ---- store: position p holds time sample n = drev16(p) ----
  const float inv = 2.44140625e-4f;  // 1/4096
  float4* og = O4 + (size_t)b * 4096 * 32 + q;
  #pragma unroll
  for (int i = 0; i < 8; i++) {
    int p8 = (tid << 3) | i;
    float2 va = Za[SWZ(p8)];
    float2 vb = Zb[SWZ(p8)];
    int n = drev16(p8);
    og[(size_t)n * 32] = make_float4(va.x * inv, -va.y * inv, vb.x * inv, -vb.y * inv);
  }
}

extern "C" void kernel_launch(void* const* d_in, const int* in_sizes, int n_in,
                              void* d_out, int out_size, void* d_ws, size_t ws_size,
                              hipStream_t stream) {
  (void)in_sizes; (void)n_in; (void)d_ws; (void)ws_size; (void)out_size;
  const float4* x = (const float4*)d_in[0];
  float4* out = (float4*)d_out;
  // 64 batches x 32 float4-columns = 2048 blocks, 512 threads each.
  fourier_topk_kernel<<<dim3(2048), dim3(512), 0, stream>>>(x, out);
}

// Round 2
// 919.410 us; speedup vs baseline: 1.1635x; 1.1635x over previous
//
#include <hip/hip_runtime.h>

// FourierBlock: per (b, c): rfft(4096) -> keep top-16 |X| bins -> irfft.
//
// Round 1 -> 2 change: the single-kernel version read/wrote 16B per 512B row
// (C-inner layout) -> 8-11x HBM line amplification (FETCH 1.10GB / WRITE
// 1.41GB vs 134MB compulsory). Now a 3-kernel pipeline, fully coalesced:
//   1. transpose_LC : x[B,L,C] -> xT[B,C,L] in d_ws
//   2. fourier_topk : per (b, 4 channels) block reads 4 contiguous 16KB rows,
//      FFT/top-16/iFFT in LDS, writes results IN-PLACE to the same xT rows
//   3. transpose_CL : xT -> out[B,L,C]

#define SWZ(i) ((i) ^ (((i) >> 4) & 15))

__device__ __forceinline__ int drev16(int x) {
  // reverse the three base-16 digits of a 12-bit index (involution)
  return ((x & 15) << 8) | (x & 0xF0) | ((x >> 8) & 15);
}

__device__ __forceinline__ float2 cmulf(float2 a, float c, float s) {
  return make_float2(a.x * c - a.y * s, a.x * s + a.y * c);
}

__device__ __forceinline__ void bfly4(float2& a0, float2& a1, float2& a2, float2& a3) {
  float ar = a0.x + a2.x, ai = a0.y + a2.y;
  float br = a0.x - a2.x, bi = a0.y - a2.y;
  float cr = a1.x + a3.x, ci = a1.y + a3.y;
  float dr = a1.x - a3.x, di = a1.y - a3.y;
  a0 = make_float2(ar + cr, ai + ci);
  a1 = make_float2(br + di, bi - dr);   // b - i*d
  a2 = make_float2(ar - cr, ai - ci);
  a3 = make_float2(br - di, bi + dr);   // b + i*d
}

// 16-point DIF DFT in registers; output slot s holds bin rev4(s).
__device__ __forceinline__ void dft16(float2* v) {
  const float C16[10] = {1.f, 0.9238795325112867f, 0.7071067811865476f, 0.3826834323650898f, 0.f,
                         -0.3826834323650898f, -0.7071067811865476f, -0.9238795325112867f, -1.f,
                         -0.9238795325112867f};
  const float S16[10] = {0.f, -0.3826834323650898f, -0.7071067811865476f, -0.9238795325112867f, -1.f,
                         -0.9238795325112867f, -0.7071067811865476f, -0.3826834323650898f, 0.f,
                         0.3826834323650898f};
  #pragma unroll
  for (int j2 = 0; j2 < 4; j2++) {
    bfly4(v[j2], v[j2 + 4], v[j2 + 8], v[j2 + 12]);
    if (j2 > 0) {
      v[j2 + 4]  = cmulf(v[j2 + 4],  C16[j2],     S16[j2]);
      v[j2 + 8]  = cmulf(v[j2 + 8],  C16[2 * j2], S16[2 * j2]);
      v[j2 + 12] = cmulf(v[j2 + 12], C16[3 * j2], S16[3 * j2]);
    }
  }
  #pragma unroll
  for (int r2 = 0; r2 < 4; r2++) bfly4(v[4 * r2], v[4 * r2 + 1], v[4 * r2 + 2], v[4 * r2 + 3]);
}

// One radix-16 DIF pass over a span; M = twiddle span (0 = last pass, none).
template <int STRIDE, int M>
__device__ __forceinline__ void fft_pass(float2* Zl, int base, int j) {
  const int kRev4[16] = {0, 4, 8, 12, 1, 5, 9, 13, 2, 6, 10, 14, 3, 7, 11, 15};
  float2 v[16];
  #pragma unroll
  for (int p = 0; p < 16; p++) v[p] = Zl[SWZ(base + j + STRIDE * p)];
  dft16(v);
  #pragma unroll
  for (int r = 0; r < 16; r++) {
    float2 u = v[kRev4[r]];
    if (M > 0 && r > 0) {
      int a = (j * r) & (M - 1);
      if (a > M / 2) a -= M;
      float ang = (float)a * (-6.2831853071795864769f / (float)M);
      float s, c;
      __sincosf(ang, &s, &c);
      u = cmulf(u, c, s);
    }
    Zl[SWZ(base + j + STRIDE * r)] = u;
  }
}

// ---------------- transpose kernels ----------------
// x[b][l][c] (C=128 inner) <-> xT[b][c][l] (L=4096 inner). Tile: 32 L x 128 C.

__global__ __launch_bounds__(256) void transpose_LC(
    const float4* __restrict__ X4, float4* __restrict__ T4) {
  __shared__ float tile[32 * 132];
  const int t = threadIdx.x;
  const int b = blockIdx.x >> 7;
  const int l0 = (blockIdx.x & 127) << 5;
  const float4* src = X4 + ((size_t)b * 4096 + l0) * 32;
  #pragma unroll
  for (int k = 0; k < 4; k++) {
    int idx = t + 256 * k;
    int l = idx >> 5, cf4 = idx & 31;
    float4 v = src[l * 32 + cf4];
    const float* a = (const float*)&v;
    #pragma unroll
    for (int j = 0; j < 4; j++) tile[l * 132 + 4 * cf4 + j] = a[j];
  }
  __syncthreads();
  float4* dst = T4 + (size_t)b * 128 * 1024 + (l0 >> 2);
  #pragma unroll
  for (int k = 0; k < 4; k++) {
    int idx = t + 256 * k;
    int c = idx >> 3, f = idx & 7;
    float4 w;
    float* o = (float*)&w;
    #pragma unroll
    for (int j = 0; j < 4; j++) o[j] = tile[(4 * f + j) * 132 + c];
    dst[(size_t)c * 1024 + f] = w;
  }
}

__global__ __launch_bounds__(256) void transpose_CL(
    const float4* __restrict__ T4, float4* __restrict__ O4) {
  __shared__ float tile[32 * 132];
  const int t = threadIdx.x;
  const int b = blockIdx.x >> 7;
  const int l0 = (blockIdx.x & 127) << 5;
  const float4* src = T4 + (size_t)b * 128 * 1024 + (l0 >> 2);
  #pragma unroll
  for (int k = 0; k < 4; k++) {
    int idx = t + 256 * k;
    int c = idx >> 3, f = idx & 7;
    float4 v = src[(size_t)c * 1024 + f];
    const float* a = (const float*)&v;
    #pragma unroll
    for (int j = 0; j < 4; j++) tile[(4 * f + j) * 132 + c] = a[j];
  }
  __syncthreads();
  float4* dst = O4 + ((size_t)b * 4096 + l0) * 32;
  #pragma unroll
  for (int k = 0; k < 4; k++) {
    int idx = t + 256 * k;
    int l = idx >> 5, cf4 = idx & 31;
    float4 w;
    float* o = (float*)&w;
    #pragma unroll
    for (int j = 0; j < 4; j++) o[j] = tile[l * 132 + 4 * cf4 + j];
    dst[l * 32 + cf4] = w;
  }
}

// ---------------- main FFT/top-k kernel (reads & writes xT in-place) --------

__global__ __launch_bounds__(512, 4) void fourier_topk_kernel(
    float4* __restrict__ T4) {
  __shared__ float2 Za[4096];
  __shared__ float2 Zb[4096];

  const int tid = threadIdx.x;
  const int b = blockIdx.x >> 5;
  const int q = blockIdx.x & 31;             // 4-channel group
  const size_t rowbase = ((size_t)b * 128 + 4 * q) * 1024;  // float4 units

  // ---- load: 4 contiguous rows; (ch0,ch1) -> Za, (ch2,ch3) -> Zb ----
  #pragma unroll
  for (int k = 0; k < 4; k++) {
    int idx = tid + 512 * k;
    int hf = idx >> 10, p = idx & 1023;
    float4 v0 = T4[rowbase + (size_t)(2 * hf + 0) * 1024 + p];
    float4 v1 = T4[rowbase + (size_t)(2 * hf + 1) * 1024 + p];
    const float* a0 = (const float*)&v0;
    const float* a1 = (const float*)&v1;
    float2* Zt = hf ? Zb : Za;
    #pragma unroll
    for (int j = 0; j < 4; j++) Zt[SWZ(4 * p + j)] = make_float2(a0[j], a1[j]);
  }
  __syncthreads();

  const int h = tid >> 8;      // half: 0 -> Za, 1 -> Zb
  const int lt = tid & 255;    // thread id within half
  float2* Zl = h ? Zb : Za;

  // ---- forward FFT (3 radix-16 passes), output hex-digit-reversed ----
  fft_pass<256, 4096>(Zl, 0, lt);
  __syncthreads();
  fft_pass<16, 256>(Zl, (lt >> 4) << 8, lt & 15);
  __syncthreads();
  fft_pass<1, 0>(Zl, lt << 4, 0);
  __syncthreads();

  // ---- top-16 selection: wave 0 of half = channel 0, wave 1 = channel 1 ----
  const int wv = lt >> 6;      // wave within half
  const int lane = lt & 63;
  int rF = 0; float rA = 0.f, rB = 0.f;   // captured winner (lanes 0..15)

  if (wv < 2) {
    const int ch = wv;
    float m2[32];
    #pragma unroll
    for (int k = 0; k < 32; k++) {
      int f = lane + (k << 6);
      float2 P = Zl[SWZ(drev16(f))];
      float2 Q = Zl[SWZ(drev16((4096 - f) & 4095))];
      float xr = ch ? (P.y + Q.y) : (P.x + Q.x);
      float xi = ch ? (Q.x - P.x) : (P.y - Q.y);
      m2[k] = xr * xr + xi * xi;   // 4*|X|^2 (uniform scale, ordering only)
    }
    float m2x = -1.f;              // bin f=2048 (Nyquist), lane 0 only
    if (lane == 0) {
      float2 P = Zl[SWZ(8)];       // drev16(2048) == 8
      float t = ch ? P.y : P.x;
      m2x = 4.f * t * t;
    }
    for (int r = 0; r < 16; r++) {
      float bv = -1e30f; int bf = 0;
      #pragma unroll
      for (int k = 0; k < 32; k++) {
        int f = lane + (k << 6);
        if (m2[k] > bv) { bv = m2[k]; bf = f; }   // ascending k: ties -> lower f
      }
      if (m2x > bv) { bv = m2x; bf = 2048; }
      #pragma unroll
      for (int off = 32; off; off >>= 1) {
        float ov = __shfl_down(bv, off);
        int   of = __shfl_down(bf, off);
        if (ov > bv || (ov == bv && of < bf)) { bv = ov; bf = of; }
      }
      bf = __shfl(bf, 0);          // broadcast winner bin
      if (lane == r) {             // capture X[bf] in lane r's registers
        rF = bf;
        float2 P = Zl[SWZ(drev16(bf))];
        float2 Q = Zl[SWZ(drev16((4096 - bf) & 4095))];
        rA = ch ? 0.5f * (P.y + Q.y) : 0.5f * (P.x + Q.x);
        rB = ch ? 0.5f * (Q.x - P.x) : 0.5f * (P.y - Q.y);
      }
      if (bf == 2048) {
        if (lane == 0) m2x = -2.f;
      } else if ((bf & 63) == lane) {
        int kk = bf >> 6;
        #pragma unroll
        for (int k = 0; k < 32; k++) if (k == kk) m2[k] = -2.f;
      }
    }
  }
  __syncthreads();   // all spectrum reads done

  // ---- build C = conj(masked Hermitian spectrum), natural order ----
  #pragma unroll
  for (int k = 0; k < 8; k++) {
    int n = tid + 512 * k;
    Za[n] = make_float2(0.f, 0.f);
    Zb[n] = make_float2(0.f, 0.f);
  }
  __syncthreads();
  if (wv == 0 && lane < 16) {      // channel 0: C[f] = conj(X0)
    int f = rF;
    Zl[SWZ(f)] = make_float2(rA, -rB);
    if (f != 0 && f != 2048) Zl[SWZ(4096 - f)] = make_float2(rA, rB);
  }
  __syncthreads();
  if (wv == 1 && lane < 16) {      // channel 1: C[f] += conj(i*X1)
    int f = rF;
    float2 u = Zl[SWZ(f)];
    u.x -= rB; u.y -= rA;
    Zl[SWZ(f)] = u;
    if (f != 0 && f != 2048) {
      float2 u2 = Zl[SWZ(4096 - f)];
      u2.x += rB; u2.y -= rA;
      Zl[SWZ(4096 - f)] = u2;
    }
  }
  __syncthreads();

  // ---- inverse: ifft(Z') = conj(fft(conj(Z')))/N ----
  fft_pass<256, 4096>(Zl, 0, lt);
  __syncthreads();
  fft_pass<16, 256>(Zl, (lt >> 4) << 8, lt & 15);
  __syncthreads();
  fft_pass<1, 0>(Zl, lt << 4, 0);
  __syncthreads();

  // ---- store in-place to the same xT rows, coalesced along L ----
  // time sample n lives at LDS position drev16(n)
  const float inv = 2.44140625e-4f;  // 1/4096
  #pragma unroll
  for (int k = 0; k < 4; k++) {
    int idx = tid + 512 * k;
    int hf = idx >> 10, p4 = idx & 1023;
    float2* Zt = hf ? Zb : Za;
    float4 w0, w1;
    float* o0 = (float*)&w0;
    float* o1 = (float*)&w1;
    #pragma unroll
    for (int j = 0; j < 4; j++) {
      float2 v = Zt[SWZ(drev16(4 * p4 + j))];
      o0[j] = v.x * inv;
      o1[j] = -v.y * inv;
    }
    T4[rowbase + (size_t)(2 * hf + 0) * 1024 + p4] = w0;
    T4[rowbase + (size_t)(2 * hf + 1) * 1024 + p4] = w1;
  }
}

extern "C" void kernel_launch(void* const* d_in, const int* in_sizes, int n_in,
                              void* d_out, int out_size, void* d_ws, size_t ws_size,
                              hipStream_t stream) {
  (void)in_sizes; (void)n_in; (void)ws_size; (void)out_size;
  const float4* x = (const float4*)d_in[0];
  float4* out = (float4*)d_out;
  float4* xT = (float4*)d_ws;   // 64*128*4096 floats = 128 MiB

  transpose_LC<<<dim3(64 * 128), dim3(256), 0, stream>>>(x, xT);
  fourier_topk_kernel<<<dim3(64 * 32), dim3(512), 0, stream>>>(xT);
  transpose_CL<<<dim3(64 * 128), dim3(256), 0, stream>>>(xT, out);
}

// Round 3
// 634.703 us; speedup vs baseline: 1.6854x; 1.4486x over previous
//
#include <hip/hip_runtime.h>

// FourierBlock: per (b, c): rfft(4096) -> keep top-16 |X| bins -> irfft.
//
// 3-kernel pipeline, fully coalesced HBM access:
//   1. transpose_LC : x[B,L,C] -> xT[B,C,L] in d_ws
//   2. fourier_topk : per (b, 4 channels) block reads 4 contiguous 16KB rows,
//      FFT/top-16/iFFT in LDS, writes results IN-PLACE to the same xT rows
//   3. transpose_CL : xT -> out[B,L,C]
//
// Round 2 -> 3 change: __launch_bounds__(512, 4) made the compiler cap the
// fourier kernel at 64 VGPRs and spill m2[32] + v[16] to scratch -> 1.46 GB
// of HBM writes, 2.7% occupancy, VALUBusy 1.3%. Occupancy is LDS-limited to
// 2 blocks/CU regardless, so declare (512, 2) -> VGPR cap >=128, no spill.

#define SWZ(i) ((i) ^ (((i) >> 4) & 15))

__device__ __forceinline__ int drev16(int x) {
  // reverse the three base-16 digits of a 12-bit index (involution)
  return ((x & 15) << 8) | (x & 0xF0) | ((x >> 8) & 15);
}

__device__ __forceinline__ float2 cmulf(float2 a, float c, float s) {
  return make_float2(a.x * c - a.y * s, a.x * s + a.y * c);
}

__device__ __forceinline__ void bfly4(float2& a0, float2& a1, float2& a2, float2& a3) {
  float ar = a0.x + a2.x, ai = a0.y + a2.y;
  float br = a0.x - a2.x, bi = a0.y - a2.y;
  float cr = a1.x + a3.x, ci = a1.y + a3.y;
  float dr = a1.x - a3.x, di = a1.y - a3.y;
  a0 = make_float2(ar + cr, ai + ci);
  a1 = make_float2(br + di, bi - dr);   // b - i*d
  a2 = make_float2(ar - cr, ai - ci);
  a3 = make_float2(br - di, bi + dr);   // b + i*d
}

// 16-point DIF DFT in registers; output slot s holds bin rev4(s).
__device__ __forceinline__ void dft16(float2* v) {
  const float C16[10] = {1.f, 0.9238795325112867f, 0.7071067811865476f, 0.3826834323650898f, 0.f,
                         -0.3826834323650898f, -0.7071067811865476f, -0.9238795325112867f, -1.f,
                         -0.9238795325112867f};
  const float S16[10] = {0.f, -0.3826834323650898f, -0.7071067811865476f, -0.9238795325112867f, -1.f,
                         -0.9238795325112867f, -0.7071067811865476f, -0.3826834323650898f, 0.f,
                         0.3826834323650898f};
  #pragma unroll
  for (int j2 = 0; j2 < 4; j2++) {
    bfly4(v[j2], v[j2 + 4], v[j2 + 8], v[j2 + 12]);
    if (j2 > 0) {
      v[j2 + 4]  = cmulf(v[j2 + 4],  C16[j2],     S16[j2]);
      v[j2 + 8]  = cmulf(v[j2 + 8],  C16[2 * j2], S16[2 * j2]);
      v[j2 + 12] = cmulf(v[j2 + 12], C16[3 * j2], S16[3 * j2]);
    }
  }
  #pragma unroll
  for (int r2 = 0; r2 < 4; r2++) bfly4(v[4 * r2], v[4 * r2 + 1], v[4 * r2 + 2], v[4 * r2 + 3]);
}

// One radix-16 DIF pass over a span; M = twiddle span (0 = last pass, none).
template <int STRIDE, int M>
__device__ __forceinline__ void fft_pass(float2* Zl, int base, int j) {
  const int kRev4[16] = {0, 4, 8, 12, 1, 5, 9, 13, 2, 6, 10, 14, 3, 7, 11, 15};
  float2 v[16];
  #pragma unroll
  for (int p = 0; p < 16; p++) v[p] = Zl[SWZ(base + j + STRIDE * p)];
  dft16(v);
  #pragma unroll
  for (int r = 0; r < 16; r++) {
    float2 u = v[kRev4[r]];
    if (M > 0 && r > 0) {
      int a = (j * r) & (M - 1);
      if (a > M / 2) a -= M;
      float ang = (float)a * (-6.2831853071795864769f / (float)M);
      float s, c;
      __sincosf(ang, &s, &c);
      u = cmulf(u, c, s);
    }
    Zl[SWZ(base + j + STRIDE * r)] = u;
  }
}

// ---------------- transpose kernels ----------------
// x[b][l][c] (C=128 inner) <-> xT[b][c][l] (L=4096 inner). Tile: 32 L x 128 C.

__global__ __launch_bounds__(256) void transpose_LC(
    const float4* __restrict__ X4, float4* __restrict__ T4) {
  __shared__ float tile[32 * 132];
  const int t = threadIdx.x;
  const int b = blockIdx.x >> 7;
  const int l0 = (blockIdx.x & 127) << 5;
  const float4* src = X4 + ((size_t)b * 4096 + l0) * 32;
  #pragma unroll
  for (int k = 0; k < 4; k++) {
    int idx = t + 256 * k;
    int l = idx >> 5, cf4 = idx & 31;
    float4 v = src[l * 32 + cf4];
    const float* a = (const float*)&v;
    #pragma unroll
    for (int j = 0; j < 4; j++) tile[l * 132 + 4 * cf4 + j] = a[j];
  }
  __syncthreads();
  float4* dst = T4 + (size_t)b * 128 * 1024 + (l0 >> 2);
  #pragma unroll
  for (int k = 0; k < 4; k++) {
    int idx = t + 256 * k;
    int c = idx >> 3, f = idx & 7;
    float4 w;
    float* o = (float*)&w;
    #pragma unroll
    for (int j = 0; j < 4; j++) o[j] = tile[(4 * f + j) * 132 + c];
    dst[(size_t)c * 1024 + f] = w;
  }
}

__global__ __launch_bounds__(256) void transpose_CL(
    const float4* __restrict__ T4, float4* __restrict__ O4) {
  __shared__ float tile[32 * 132];
  const int t = threadIdx.x;
  const int b = blockIdx.x >> 7;
  const int l0 = (blockIdx.x & 127) << 5;
  const float4* src = T4 + (size_t)b * 128 * 1024 + (l0 >> 2);
  #pragma unroll
  for (int k = 0; k < 4; k++) {
    int idx = t + 256 * k;
    int c = idx >> 3, f = idx & 7;
    float4 v = src[(size_t)c * 1024 + f];
    const float* a = (const float*)&v;
    #pragma unroll
    for (int j = 0; j < 4; j++) tile[(4 * f + j) * 132 + c] = a[j];
  }
  __syncthreads();
  float4* dst = O4 + ((size_t)b * 4096 + l0) * 32;
  #pragma unroll
  for (int k = 0; k < 4; k++) {
    int idx = t + 256 * k;
    int l = idx >> 5, cf4 = idx & 31;
    float4 w;
    float* o = (float*)&w;
    #pragma unroll
    for (int j = 0; j < 4; j++) o[j] = tile[l * 132 + 4 * cf4 + j];
    dst[l * 32 + cf4] = w;
  }
}

// ---------------- main FFT/top-k kernel (reads & writes xT in-place) --------

__global__ __launch_bounds__(512, 2) void fourier_topk_kernel(
    float4* __restrict__ T4) {
  __shared__ float2 Za[4096];
  __shared__ float2 Zb[4096];

  const int tid = threadIdx.x;
  const int b = blockIdx.x >> 5;
  const int q = blockIdx.x & 31;             // 4-channel group
  const size_t rowbase = ((size_t)b * 128 + 4 * q) * 1024;  // float4 units

  // ---- load: 4 contiguous rows; (ch0,ch1) -> Za, (ch2,ch3) -> Zb ----
  #pragma unroll
  for (int k = 0; k < 4; k++) {
    int idx = tid + 512 * k;
    int hf = idx >> 10, p = idx & 1023;
    float4 v0 = T4[rowbase + (size_t)(2 * hf + 0) * 1024 + p];
    float4 v1 = T4[rowbase + (size_t)(2 * hf + 1) * 1024 + p];
    const float* a0 = (const float*)&v0;
    const float* a1 = (const float*)&v1;
    float2* Zt = hf ? Zb : Za;
    #pragma unroll
    for (int j = 0; j < 4; j++) Zt[SWZ(4 * p + j)] = make_float2(a0[j], a1[j]);
  }
  __syncthreads();

  const int h = tid >> 8;      // half: 0 -> Za, 1 -> Zb
  const int lt = tid & 255;    // thread id within half
  float2* Zl = h ? Zb : Za;

  // ---- forward FFT (3 radix-16 passes), output hex-digit-reversed ----
  fft_pass<256, 4096>(Zl, 0, lt);
  __syncthreads();
  fft_pass<16, 256>(Zl, (lt >> 4) << 8, lt & 15);
  __syncthreads();
  fft_pass<1, 0>(Zl, lt << 4, 0);
  __syncthreads();

  // ---- top-16 selection: wave 0 of half = channel 0, wave 1 = channel 1 ----
  const int wv = lt >> 6;      // wave within half
  const int lane = lt & 63;
  int rF = 0; float rA = 0.f, rB = 0.f;   // captured winner (lanes 0..15)

  if (wv < 2) {
    const int ch = wv;
    float m2[32];
    #pragma unroll
    for (int k = 0; k < 32; k++) {
      int f = lane + (k << 6);
      float2 P = Zl[SWZ(drev16(f))];
      float2 Q = Zl[SWZ(drev16((4096 - f) & 4095))];
      float xr = ch ? (P.y + Q.y) : (P.x + Q.x);
      float xi = ch ? (Q.x - P.x) : (P.y - Q.y);
      m2[k] = xr * xr + xi * xi;   // 4*|X|^2 (uniform scale, ordering only)
    }
    float m2x = -1.f;              // bin f=2048 (Nyquist), lane 0 only
    if (lane == 0) {
      float2 P = Zl[SWZ(8)];       // drev16(2048) == 8
      float t = ch ? P.y : P.x;
      m2x = 4.f * t * t;
    }
    for (int r = 0; r < 16; r++) {
      float bv = -1e30f; int bf = 0;
      #pragma unroll
      for (int k = 0; k < 32; k++) {
        int f = lane + (k << 6);
        if (m2[k] > bv) { bv = m2[k]; bf = f; }   // ascending k: ties -> lower f
      }
      if (m2x > bv) { bv = m2x; bf = 2048; }
      #pragma unroll
      for (int off = 32; off; off >>= 1) {
        float ov = __shfl_down(bv, off);
        int   of = __shfl_down(bf, off);
        if (ov > bv || (ov == bv && of < bf)) { bv = ov; bf = of; }
      }
      bf = __shfl(bf, 0);          // broadcast winner bin
      if (lane == r) {             // capture X[bf] in lane r's registers
        rF = bf;
        float2 P = Zl[SWZ(drev16(bf))];
        float2 Q = Zl[SWZ(drev16((4096 - bf) & 4095))];
        rA = ch ? 0.5f * (P.y + Q.y) : 0.5f * (P.x + Q.x);
        rB = ch ? 0.5f * (Q.x - P.x) : 0.5f * (P.y - Q.y);
      }
      if (bf == 2048) {
        if (lane == 0) m2x = -2.f;
      } else if ((bf & 63) == lane) {
        int kk = bf >> 6;
        #pragma unroll
        for (int k = 0; k < 32; k++) if (k == kk) m2[k] = -2.f;
      }
    }
  }
  __syncthreads();   // all spectrum reads done

  // ---- build C = conj(masked Hermitian spectrum), natural order ----
  #pragma unroll
  for (int k = 0; k < 8; k++) {
    int n = tid + 512 * k;
    Za[n] = make_float2(0.f, 0.f);
    Zb[n] = make_float2(0.f, 0.f);
  }
  __syncthreads();
  if (wv == 0 && lane < 16) {      // channel 0: C[f] = conj(X0)
    int f = rF;
    Zl[SWZ(f)] = make_float2(rA, -rB);
    if (f != 0 && f != 2048) Zl[SWZ(4096 - f)] = make_float2(rA, rB);
  }
  __syncthreads();
  if (wv == 1 && lane < 16) {      // channel 1: C[f] += conj(i*X1)
    int f = rF;
    float2 u = Zl[SWZ(f)];
    u.x -= rB; u.y -= rA;
    Zl[SWZ(f)] = u;
    if (f != 0 && f != 2048) {
      float2 u2 = Zl[SWZ(4096 - f)];
      u2.x += rB; u2.y -= rA;
      Zl[SWZ(4096 - f)] = u2;
    }
  }
  __syncthreads();

  // ---- inverse: ifft(Z') = conj(fft(conj(Z')))/N ----
  fft_pass<256, 4096>(Zl, 0, lt);
  __syncthreads();
  fft_pass<16, 256>(Zl, (lt >> 4) << 8, lt & 15);
  __syncthreads();
  fft_pass<1, 0>(Zl, lt << 4, 0);
  __syncthreads();

  // ---- store in-place to the same xT rows, coalesced along L ----
  // time sample n lives at LDS position drev16(n)
  const float inv = 2.44140625e-4f;  // 1/4096
  #pragma unroll
  for (int k = 0; k < 4; k++) {
    int idx = tid + 512 * k;
    int hf = idx >> 10, p4 = idx & 1023;
    float2* Zt = hf ? Zb : Za;
    float4 w0, w1;
    float* o0 = (float*)&w0;
    float* o1 = (float*)&w1;
    #pragma unroll
    for (int j = 0; j < 4; j++) {
      float2 v = Zt[SWZ(drev16(4 * p4 + j))];
      o0[j] = v.x * inv;
      o1[j] = -v.y * inv;
    }
    T4[rowbase + (size_t)(2 * hf + 0) * 1024 + p4] = w0;
    T4[rowbase + (size_t)(2 * hf + 1) * 1024 + p4] = w1;
  }
}

extern "C" void kernel_launch(void* const* d_in, const int* in_sizes, int n_in,
                              void* d_out, int out_size, void* d_ws, size_t ws_size,
                              hipStream_t stream) {
  (void)in_sizes; (void)n_in; (void)ws_size; (void)out_size;
  const float4* x = (const float4*)d_in[0];
  float4* out = (float4*)d_out;
  float4* xT = (float4*)d_ws;   // 64*128*4096 floats = 128 MiB

  transpose_LC<<<dim3(64 * 128), dim3(256), 0, stream>>>(x, xT);
  fourier_topk_kernel<<<dim3(64 * 32), dim3(512), 0, stream>>>(xT);
  transpose_CL<<<dim3(64 * 128), dim3(256), 0, stream>>>(xT, out);
}